// Round 5
// baseline (244.882 us; speedup 1.0000x reference)
//
#include <hip/hip_runtime.h>
#include <math.h>

#define C  2048
#define L  4096
#define L2 2048
#define CW3 6144  // C*3

// ---- d_ws layout (float offsets) ----
constexpr size_t OFF_RS_A = 0;      // 2048
constexpr size_t OFF_RQ_A = 2048;   // 2048
constexpr size_t OFF_RS_B = 4096;   // 2048
constexpr size_t OFF_RQ_B = 6144;   // 2048
constexpr size_t OFF_SCAL = 8192;   // 16: [0]=meanA [1]=coefA [2]=meanB [3]=coefB [4]=sum(fc_b)
// ---- atomic region (zeroed by w1 blocks 4096..4113): floats 8208..26639 ----
constexpr size_t OFF_CW   = 8208;   // 2048  colsum(fc_w)   (atomics in w2)
constexpr size_t OFF_G    = 10256;  // 6144                 (atomics in w3)
constexpr size_t OFF_H    = 16400;  // 6144                 (atomics in w3)
constexpr size_t OFF_V    = 22544;  // 2048                 (atomics in w4)
constexpr size_t OFF_O2   = 24592;  // 2048                 (atomics in w4)
// ---- plain ----
constexpr size_t OFF_S    = 26640;  // 2048
constexpr size_t OFF_U    = 28688;  // 6144
constexpr size_t OFF_MIX  = 34832;  // 2048
// total 36880 floats = 147.5 KB (proven ws_size >= 164 KB)

// pooled tensors staged in d_out (exactly fills it; overwritten by w7)
constexpr size_t PA_OFF = 0;         // pooled input  2048x2048
constexpr size_t PB_OFF = 4194304;   // pooled insum  2048x2048

__device__ __forceinline__ float wredf(float v) {
#pragma unroll
  for (int o = 32; o; o >>= 1) v += __shfl_down(v, o, 64);
  return v;
}
__device__ __forceinline__ double wredd(double v) {
#pragma unroll
  for (int o = 32; o; o >>= 1) v += __shfl_down(v, o, 64);
  return v;
}
__device__ __forceinline__ float sigm(float x) { return 1.f / (1.f + expf(-x)); }
__device__ __forceinline__ float simam1(float x, float m, float cf) {
  float d = x - m;
  float y = d * d * cf + 0.5f;
  return x * (1.f + 1.f / (1.f + expf(-y)));
}

// ===== w1: rowstats + pooled write (4096) | zero atomic region (18) =====
__global__ void w1(const float* __restrict__ A, const float* __restrict__ B,
                   float* __restrict__ ws, float* __restrict__ dout) {
  int u = blockIdx.x;
  int tid = threadIdx.x;
  if (u < 4096) {
    __shared__ float sm[8];
    const float* src = (u < 2048) ? A : B;
    int row = u & 2047;
    const float4* p = (const float4*)(src + (size_t)row * L);
    float4* pool = (float4*)(dout + ((u < 2048) ? PA_OFF : PB_OFF) + (size_t)row * L2);
    float s = 0.f, q = 0.f;
#pragma unroll
    for (int i = tid; i < L2 / 4; i += 256) {
      float4 v0 = p[2 * i], v1 = p[2 * i + 1];
      s += ((v0.x + v0.y) + (v0.z + v0.w)) + ((v1.x + v1.y) + (v1.z + v1.w));
      q += (v0.x * v0.x + v0.y * v0.y) + (v0.z * v0.z + v0.w * v0.w) +
           (v1.x * v1.x + v1.y * v1.y) + (v1.z * v1.z + v1.w * v1.w);
      float4 pm;
      pm.x = (v0.x + v0.y) * 0.5f;
      pm.y = (v0.z + v0.w) * 0.5f;
      pm.z = (v1.x + v1.y) * 0.5f;
      pm.w = (v1.z + v1.w) * 0.5f;
      pool[i] = pm;
    }
    s = wredf(s); q = wredf(q);
    int lane = tid & 63, wv = tid >> 6;
    if (!lane) { sm[wv] = s; sm[4 + wv] = q; }
    __syncthreads();
    if (!tid) {
      float* rs = ws + ((u < 2048) ? OFF_RS_A : OFF_RS_B);
      float* rq = ws + ((u < 2048) ? OFF_RQ_A : OFF_RQ_B);
      rs[row] = sm[0] + sm[1] + sm[2] + sm[3];
      rq[row] = sm[4] + sm[5] + sm[6] + sm[7];
    }
  } else {
    // zero CW..O2: 18432 floats = 4608 float4, 18 blocks x 256 threads x 1 float4
    float4* wz = (float4*)(ws + OFF_CW);
    int i = (u - 4096) * 256 + tid;
    wz[i] = make_float4(0.f, 0.f, 0.f, 0.f);
  }
}

// ===== w2: s vector (512) | global scalars (1) | CW atomics (256) =====
__global__ void w2(const float* __restrict__ fc_w, const float* __restrict__ fc_b,
                   float* __restrict__ ws) {
  int u = blockIdx.x, tid = threadIdx.x;
  int lane = tid & 63, wv = tid >> 6;
  if (u < 512) {
    __shared__ float sl[16];
    int r0 = u * 4;
    const float4* rx = (const float4*)(ws + OFF_RS_A);
    const float4* w4 = (const float4*)fc_w;
    float a0 = 0.f, a1 = 0.f, a2 = 0.f, a3 = 0.f;
#pragma unroll
    for (int i = tid; i < C / 4; i += 256) {
      float4 r = rx[i];
      float4 q0 = w4[(size_t)(r0 + 0) * 512 + i];
      float4 q1 = w4[(size_t)(r0 + 1) * 512 + i];
      float4 q2 = w4[(size_t)(r0 + 2) * 512 + i];
      float4 q3 = w4[(size_t)(r0 + 3) * 512 + i];
      a0 += q0.x * r.x + q0.y * r.y + q0.z * r.z + q0.w * r.w;
      a1 += q1.x * r.x + q1.y * r.y + q1.z * r.z + q1.w * r.w;
      a2 += q2.x * r.x + q2.y * r.y + q2.z * r.z + q2.w * r.w;
      a3 += q3.x * r.x + q3.y * r.y + q3.z * r.z + q3.w * r.w;
    }
    a0 = wredf(a0); a1 = wredf(a1); a2 = wredf(a2); a3 = wredf(a3);
    if (!lane) { sl[wv] = a0; sl[4 + wv] = a1; sl[8 + wv] = a2; sl[12 + wv] = a3; }
    __syncthreads();
    if (tid < 4) {
      float s_ = sl[tid * 4 + 0] + sl[tid * 4 + 1] + sl[tid * 4 + 2] + sl[tid * 4 + 3];
      ws[OFF_S + r0 + tid] = 0.5f * s_ + (float)L2 * fc_b[r0 + tid];
    }
  } else if (u == 512) {
    __shared__ double sd[5];
    const float* arr = ws + (wv == 0 ? OFF_RS_A : wv == 1 ? OFF_RQ_A
                                                          : wv == 2 ? OFF_RS_B : OFF_RQ_B);
    double acc = 0.0, accb = 0.0;
    for (int i = lane; i < 2048; i += 64) {
      acc += (double)arr[i];
      if (wv == 0) accb += (double)fc_b[i];
    }
    acc = wredd(acc);
    if (wv == 0) accb = wredd(accb);
    if (!lane) { sd[wv] = acc; if (wv == 0) sd[4] = accb; }
    __syncthreads();
    if (!tid) {
      const double N = (double)C * (double)L, n = N - 1.0;
      double dA = sd[1] - sd[0] * sd[0] / N;
      double dB = sd[3] - sd[2] * sd[2] / N;
      float* sc = ws + OFF_SCAL;
      sc[0] = (float)(sd[0] / N);
      sc[1] = (float)(1.0 / (4.0 * (dA / n + 1e-4)));
      sc[2] = (float)(sd[2] / N);
      sc[3] = (float)(1.0 / (4.0 * (dB / n + 1e-4)));
      sc[4] = (float)sd[4];
    }
  } else {
    int cb = u - 513;             // 0..255
    int rg = cb >> 3;             // 0..31, 64 fc_w rows each
    int col = (cb & 7) * 256 + tid;
    const float* p = fc_w + (size_t)rg * 64 * C + col;
    float acc = 0.f;
#pragma unroll 8
    for (int k = 0; k < 64; ++k) acc += p[(size_t)k * C];
    atomicAdd(ws + OFF_CW + col, acc);
  }
}

// ===== w3: g,h atomics; float4 cols; grid 32 rowgroups(64 rows) x 6 colchunks = 192 =====
__global__ void w3(const float* __restrict__ conv1_w, float* __restrict__ ws) {
  __shared__ float lcw[64], ls[64];
  int u = blockIdx.x;
  int tid = threadIdx.x;
  int cc = u % 6, rg = u / 6;      // rg 0..31, 64 rows each
  int i0 = rg * 64;
  int col4 = cc * 256 + tid;       // float4 col index 0..1535
  if (tid < 64) {
    lcw[tid] = (ws + OFF_CW)[i0 + tid];
    ls[tid] = (ws + OFF_S)[i0 + tid];
  }
  __syncthreads();
  const float4* cv = (const float4*)conv1_w;
  float4 g4 = {0.f, 0.f, 0.f, 0.f}, h4 = {0.f, 0.f, 0.f, 0.f};
#pragma unroll 8
  for (int k = 0; k < 64; ++k) {
    float4 w = cv[(size_t)(i0 + k) * 1536 + col4];
    float cwv = lcw[k], sv = ls[k];
    g4.x += cwv * w.x; g4.y += cwv * w.y; g4.z += cwv * w.z; g4.w += cwv * w.w;
    h4.x += sv * w.x;  h4.y += sv * w.y;  h4.z += sv * w.z;  h4.w += sv * w.w;
  }
  int col = col4 * 4;
  atomicAdd(ws + OFF_G + col + 0, g4.x);
  atomicAdd(ws + OFF_G + col + 1, g4.y);
  atomicAdd(ws + OFF_G + col + 2, g4.z);
  atomicAdd(ws + OFF_G + col + 3, g4.w);
  atomicAdd(ws + OFF_H + col + 0, h4.x);
  atomicAdd(ws + OFF_H + col + 1, h4.y);
  atomicAdd(ws + OFF_H + col + 2, h4.z);
  atomicAdd(ws + OFF_H + col + 3, h4.w);
}

// ===== w4: v,o2 from pooled insum; float4, 4 outputs/thread; grid 2 kb x 128 cg = 256 =====
__global__ void w4(const float* __restrict__ dout, float* __restrict__ ws) {
  __shared__ float gs[48], hs[48];
  int u = blockIdx.x;
  int tid = threadIdx.x;
  int kb = u & 1, cg = u >> 1;   // cg 0..127, 16 channels each
  int c0 = cg * 16;
  int q = kb * 256 + tid;        // float4 index 0..511
  int lane = tid & 63;
  if (tid < 48) gs[tid] = (ws + OFF_G)[c0 * 3 + tid];
  else if (tid >= 64 && tid < 112) hs[tid - 64] = (ws + OFF_H)[c0 * 3 + tid - 64];
  __syncthreads();
  float4 accv = {0.f, 0.f, 0.f, 0.f}, acco = {0.f, 0.f, 0.f, 0.f};
#pragma unroll 4
  for (int c = 0; c < 16; ++c) {
    const float* row = dout + PB_OFF + (size_t)(c0 + c) * L2;
    float4 x = ((const float4*)row)[q];
    float xlm = __shfl_up(x.w, 1, 64);
    float xrp = __shfl_down(x.x, 1, 64);
    if (lane == 0)  xlm = (q > 0) ? row[4 * q - 1] : 0.f;
    if (lane == 63) xrp = (q < 511) ? row[4 * q + 4] : 0.f;
    float g0 = gs[c * 3], g1 = gs[c * 3 + 1], g2 = gs[c * 3 + 2];
    float h0 = hs[c * 3], h1 = hs[c * 3 + 1], h2 = hs[c * 3 + 2];
    accv.x += g0 * xlm + g1 * x.x + g2 * x.y;
    accv.y += g0 * x.x + g1 * x.y + g2 * x.z;
    accv.z += g0 * x.y + g1 * x.z + g2 * x.w;
    accv.w += g0 * x.z + g1 * x.w + g2 * xrp;
    acco.x += h0 * xlm + h1 * x.x + h2 * x.y;
    acco.y += h0 * x.x + h1 * x.y + h2 * x.z;
    acco.z += h0 * x.y + h1 * x.z + h2 * x.w;
    acco.w += h0 * x.z + h1 * x.w + h2 * xrp;
  }
  int k0 = 4 * q;
  atomicAdd(ws + OFF_V + k0 + 0, accv.x);
  atomicAdd(ws + OFF_V + k0 + 1, accv.y);
  atomicAdd(ws + OFF_V + k0 + 2, accv.z);
  atomicAdd(ws + OFF_V + k0 + 3, accv.w);
  atomicAdd(ws + OFF_O2 + k0 + 0, acco.x);
  atomicAdd(ws + OFF_O2 + k0 + 1, acco.y);
  atomicAdd(ws + OFF_O2 + k0 + 2, acco.z);
  atomicAdd(ws + OFF_O2 + k0 + 3, acco.w);
}

// ===== w5: U correlations, float4 + shuffle windows, 2 rows/block (1024) =====
__global__ void w5(const float* __restrict__ dout, float* __restrict__ ws) {
  __shared__ float4 vs4[512];
  __shared__ float s12[12];
  float* vs = (float*)vs4;
  int u = blockIdx.x;
  int tid = threadIdx.x;
  int lane = tid & 63, wv = tid >> 6;
  float sb = (ws + OFF_SCAL)[4];
  for (int j = tid; j < L2; j += 256) vs[j] = (ws + OFF_V)[j] + sb;
  __syncthreads();
#pragma unroll
  for (int rr = 0; rr < 2; ++rr) {
    int row = u * 2 + rr;
    const float4* prow = (const float4*)(dout + PA_OFF + (size_t)row * L2);
    float a0 = 0.f, a1 = 0.f, a2 = 0.f;
#pragma unroll
    for (int it = 0; it < 2; ++it) {
      int i = it * 256 + tid;       // float4 index 0..511, j0 = 4i
      float4 xm = prow[i];
      float4 va = vs4[i];
      float vm1 = __shfl_up(va.w, 1, 64);     // vs[j0-1]
      float vp4 = __shfl_down(va.x, 1, 64);   // vs[j0+4]
      if (lane == 0)  vm1 = (i > 0) ? vs[4 * i - 1] : 0.f;
      if (lane == 63) vp4 = (i < 511) ? vs[4 * i + 4] : 0.f;
      a1 += xm.x * va.x + xm.y * va.y + xm.z * va.z + xm.w * va.w;
      a0 += xm.x * va.y + xm.y * va.z + xm.z * va.w + xm.w * vp4;
      a2 += xm.x * vm1 + xm.y * va.x + xm.z * va.y + xm.w * va.z;
    }
    a0 = wredf(a0); a1 = wredf(a1); a2 = wredf(a2);
    if (!lane) { s12[wv] = a0; s12[4 + wv] = a1; s12[8 + wv] = a2; }
    __syncthreads();
    if (!tid) {
      (ws + OFF_U)[row * 3 + 0] = s12[0] + s12[1] + s12[2] + s12[3];
      (ws + OFF_U)[row * 3 + 1] = s12[4] + s12[5] + s12[6] + s12[7];
      (ws + OFF_U)[row * 3 + 2] = s12[8] + s12[9] + s12[10] + s12[11];
    }
    __syncthreads();
  }
}

// ===== w6: out1 + mix =====
__global__ void w6(const float* __restrict__ conv1_w, const float* __restrict__ mix_w,
                   float* __restrict__ ws) {
  __shared__ float sl[4];
  int u = blockIdx.x;
  int tid = threadIdx.x;
  const float4* w4p = (const float4*)(conv1_w + (size_t)u * CW3);
  const float4* u4 = (const float4*)(ws + OFF_U);
  float acc = 0.f;
#pragma unroll
  for (int m = tid; m < CW3 / 4; m += 256) {
    float4 wv = w4p[m], uv = u4[m];
    acc += wv.x * uv.x + wv.y * uv.y + wv.z * uv.z + wv.w * uv.w;
  }
  acc = wredf(acc);
  int lane = tid & 63, wv = tid >> 6;
  if (!lane) sl[wv] = acc;
  __syncthreads();
  if (!tid) {
    float mfv = sigm(mix_w[0]);
    float o1 = sigm(sl[0] + sl[1] + sl[2] + sl[3]);
    float o2 = sigm((ws + OFF_O2)[u]);
    (ws + OFF_MIX)[u] = o1 * mfv + o2 * (1.f - mfv);
  }
}

// ===== w7: per-row mid-tap gate + final elementwise (overwrites d_out) =====
__global__ void w7(const float* __restrict__ input, const float* __restrict__ insum,
                   const float* __restrict__ conv1_w, float* __restrict__ out,
                   const float* __restrict__ ws) {
  __shared__ float sl[4];
  __shared__ float shov;
  int u = blockIdx.x;
  int tid = threadIdx.x;
  const float4* w4p = (const float4*)(conv1_w + (size_t)u * CW3);
  const float4* m4 = (const float4*)(ws + OFF_MIX);
  float acc = 0.f;
#pragma unroll
  for (int p = tid; p < 512; p += 256) {
    float4 f0 = w4p[3 * p], f1 = w4p[3 * p + 1], f2 = w4p[3 * p + 2];
    float4 m = m4[p];
    acc += f0.y * m.x + f1.x * m.y + f1.w * m.z + f2.z * m.w;
  }
  acc = wredf(acc);
  int lane = tid & 63, wv = tid >> 6;
  if (!lane) sl[wv] = acc;
  __syncthreads();
  if (!tid) shov = sigm(sl[0] + sl[1] + sl[2] + sl[3]);
  __syncthreads();
  float ovc = shov;
  const float* scal = ws + OFF_SCAL;
  float mA = scal[0], cA = scal[1], mB = scal[2], cB = scal[3];
  size_t base = (size_t)u * L;
  const float4* pa = (const float4*)(input + base);
  const float4* pb = (const float4*)(insum + base);
  float4* po = (float4*)(out + base);
#pragma unroll
  for (int i = tid; i < L / 4; i += 256) {
    float4 a = pa[i], b = pb[i], r;
    r.x = (simam1(a.x, mA, cA) * 0.6f + simam1(b.x, mB, cB) * 0.4f) * ovc;
    r.y = (simam1(a.y, mA, cA) * 0.6f + simam1(b.y, mB, cB) * 0.4f) * ovc;
    r.z = (simam1(a.z, mA, cA) * 0.6f + simam1(b.z, mB, cB) * 0.4f) * ovc;
    r.w = (simam1(a.w, mA, cA) * 0.6f + simam1(b.w, mB, cB) * 0.4f) * ovc;
    po[i] = r;
  }
}

extern "C" void kernel_launch(void* const* d_in, const int* in_sizes, int n_in,
                              void* d_out, int out_size, void* d_ws, size_t ws_size,
                              hipStream_t stream) {
  const float* input   = (const float*)d_in[0];
  const float* insum   = (const float*)d_in[1];
  const float* conv1_w = (const float*)d_in[2];
  const float* fc_w    = (const float*)d_in[3];
  const float* fc_b    = (const float*)d_in[4];
  const float* mix_w   = (const float*)d_in[5];
  float* out = (float*)d_out;
  float* ws  = (float*)d_ws;

  dim3 b(256);
  w1<<<4114, b, 0, stream>>>(input, insum, ws, out);         // stats+pool | zero atomics
  w2<<<769, b, 0, stream>>>(fc_w, fc_b, ws);                 // S | scalars | CW
  w3<<<192, b, 0, stream>>>(conv1_w, ws);                    // G,H (float4)
  w4<<<256, b, 0, stream>>>(out, ws);                        // V,O2 (float4)
  w5<<<1024, b, 0, stream>>>(out, ws);                       // U (float4, 2 rows/blk)
  w6<<<2048, b, 0, stream>>>(conv1_w, mix_w, ws);            // mix
  w7<<<2048, b, 0, stream>>>(input, insum, conv1_w, out, ws);// gate + final
}